// Round 3
// baseline (507.164 us; speedup 1.0000x reference)
//
#include <hip/hip_runtime.h>
#include <hip/hip_bf16.h>
#include <cstdint>

// B=64, S=2048, H=512
// in: dec[64,512] f32, enc[64,2048,512] f32, Wq[512,512] f32, Wk[512,512] f32, v[512] f32
// out: context[64,512] ++ weights[64,2048]  (163840 f32)
// ws: [0,512K) Wk bf16; [512K,640K) q f32; [640K,768K) numer f32 (unnormalized context)

typedef __attribute__((ext_vector_type(8))) short short8;
typedef __attribute__((ext_vector_type(4))) float f32x4;

__device__ __forceinline__ unsigned short f2bf(float f) {
    unsigned u = __builtin_bit_cast(unsigned, f);
    u += 0x7FFFu + ((u >> 16) & 1u);       // RNE; inputs are normal floats
    return (unsigned short)(u >> 16);
}

__device__ __forceinline__ short8 cvt8(float4 a, float4 b) {
    short8 r;
    r[0] = (short)f2bf(a.x); r[1] = (short)f2bf(a.y);
    r[2] = (short)f2bf(a.z); r[3] = (short)f2bf(a.w);
    r[4] = (short)f2bf(b.x); r[5] = (short)f2bf(b.y);
    r[6] = (short)f2bf(b.z); r[7] = (short)f2bf(b.w);
    return r;
}

__device__ __forceinline__ float tanh_fast(float x) {
    // tanh(x) = 1 - 2/(exp(2x)+1); exp overflow -> inf -> rcp -> 0 -> +1 (correct limit)
    float e = __expf(2.0f * x);
    return 1.0f - 2.0f * __builtin_amdgcn_rcpf(e + 1.0f);
}

// ---------------- kernel 1: cast W_k to bf16 + zero numer accumulator ----------------
__global__ void cast_wk_kernel(const float* __restrict__ wk, unsigned short* __restrict__ wkb,
                               float* __restrict__ numer) {
    int i = (blockIdx.x * 256 + threadIdx.x) * 4;          // 256 blocks x 256 thr x 4 = 262144
    float4 f = *(const float4*)(wk + i);
    ushort4 o;
    o.x = f2bf(f.x); o.y = f2bf(f.y); o.z = f2bf(f.z); o.w = f2bf(f.w);
    *(ushort4*)(wkb + i) = o;
    if (blockIdx.x < 32) {                                 // 32*256*4 = 32768 = 64*512
        *(float4*)(numer + i) = (float4){0.f, 0.f, 0.f, 0.f};
    }
}

// ---------------- kernel 2: q = dec @ Wq^T ----------------
__global__ void q_kernel(const float* __restrict__ dec, const float* __restrict__ wq,
                         float* __restrict__ q) {
    int b  = blockIdx.x >> 3;
    int g0 = (blockIdx.x & 7) * 64;
    int t = threadIdx.x, lane = t & 63, w = t >> 6;
    __shared__ float dls[512];
    dls[t] = dec[b * 512 + t];
    dls[t + 256] = dec[b * 512 + 256 + t];
    __syncthreads();
    #pragma unroll
    for (int gi = 0; gi < 16; ++gi) {
        int g = g0 + w + gi * 4;
        float acc = 0.f;
        #pragma unroll
        for (int it = 0; it < 2; ++it) {
            int h = (it * 64 + lane) * 4;                  // wave reads 1KiB contiguous of row g
            float4 wv = *(const float4*)(wq + (size_t)g * 512 + h);
            acc += wv.x * dls[h] + wv.y * dls[h + 1] + wv.z * dls[h + 2] + wv.w * dls[h + 3];
        }
        #pragma unroll
        for (int m = 32; m; m >>= 1) acc += __shfl_xor(acc, m, 64);
        if (lane == 0) q[b * 512 + g] = acc;
    }
}

// ---------------- kernel 3: fused keys-GEMM + tanh·v row-reduce -> raw scores ----------------
// R3: BARRIER-FREE K-loop. R2 showed barrier-per-step forces vmcnt(0) drain every
// ~160 cyc of MFMA vs ~900 cyc latency -> 3000+ cyc/step, MfmaUtil 16%.
// New structure:
//  - B (Wk bf16, L2-resident) loads GLOBAL->VGPR directly in MFMA fragment layout:
//    lane reads 16B at row(w*128+nt*16+l15), k=kk+quad*8; 4 lanes/row = 64B contiguous.
//    Ping-pong 1-deep (bf[2][8]): loads for step k+1 issued before step k's MFMAs,
//    no barrier between -> compiler's dependence-driven waitcnt = counted vmcnt,
//    loads in flight across full compute phase. No Bs LDS, no bank conflicts.
//  - A staged half-K (k 0..255, then 256..511) into As[8][64][40] bf16 (40 KiB,
//    proven conflict-free 80B-pitch layout). Only 2 barriers in the whole K-loop.
//  - LDS 46 KiB, VGPR ~245 -> 2 blocks/CU; blocks mutually hide stage/epilogue.
__launch_bounds__(256, 2)
__global__ void scores_kernel(const float* __restrict__ enc, const unsigned short* __restrict__ wkb,
                              const float* __restrict__ q, const float* __restrict__ v,
                              float* __restrict__ scores, float* __restrict__ numer) {
    __shared__ __align__(16) short As[8][64][40];  // 40 KiB, half-K of A tile
    __shared__ float q_s[512];
    __shared__ float v_s[512];
    __shared__ float red[4][64];
    __shared__ float w_lds[64];                    // exp(sc) per tile row

    int t = threadIdx.x, lane = t & 63, w = t >> 6;
    int quad = lane >> 4, l15 = lane & 15;
    int tile = blockIdx.x;
    int b = tile >> 5;                   // 32 tiles per batch
    size_t m0 = (size_t)tile * 64;

    q_s[t] = q[b * 512 + t];   q_s[t + 256] = q[b * 512 + 256 + t];
    v_s[t] = v[t];             v_s[t + 256] = v[t + 256];

    f32x4 acc[4][8];
    #pragma unroll
    for (int i = 0; i < 4; ++i)
        #pragma unroll
        for (int j = 0; j < 8; ++j)
            acc[i][j] = (f32x4){0.f, 0.f, 0.f, 0.f};

    // A stage mapping: thread t -> row t>>2, k-chunk t&3 (8 floats); half = 8 chunks of 32
    int arow = t >> 2, akq = t & 3;
    const float* aptr = enc + (m0 + arow) * 512 + akq * 8;
    #pragma unroll
    for (int h = 0; h < 8; ++h) {
        float4 fa0 = *(const float4*)(aptr + h * 32);
        float4 fa1 = *(const float4*)(aptr + h * 32 + 4);
        *(short8*)&As[h][arow][akq * 8] = cvt8(fa0, fa1);
    }

    // B fragment base pointers: lane covers rows w*128+nt*16+l15, k-chunk quad*8
    const unsigned short* bp[8];
    #pragma unroll
    for (int nt = 0; nt < 8; ++nt)
        bp[nt] = wkb + (size_t)(w * 128 + nt * 16 + l15) * 512 + quad * 8;

    __syncthreads();                               // As half-0 published

    short8 bf[2][8];
    #pragma unroll
    for (int nt = 0; nt < 8; ++nt)                 // prologue: B(0)
        bf[0][nt] = *(const short8*)(bp[nt]);

    #pragma unroll
    for (int ks = 0; ks < 16; ++ks) {
        const int cur = ks & 1, nxt = cur ^ 1;
        const int kk = ks * 32;
        if (ks == 8) {                             // restage A -> half-1 (k 256..511)
            __syncthreads();                       // all waves done reading half-0
            #pragma unroll
            for (int h = 0; h < 8; ++h) {
                float4 fa0 = *(const float4*)(aptr + 256 + h * 32);
                float4 fa1 = *(const float4*)(aptr + 256 + h * 32 + 4);
                *(short8*)&As[h][arow][akq * 8] = cvt8(fa0, fa1);
            }
            __syncthreads();                       // half-1 published
        }
        if (ks < 15) {                             // prefetch B(ks+1), in flight across MFMAs
            #pragma unroll
            for (int nt = 0; nt < 8; ++nt)
                bf[nxt][nt] = *(const short8*)(bp[nt] + kk + 32);
        }
        short8 af[4];
        #pragma unroll
        for (int mt = 0; mt < 4; ++mt)
            af[mt] = *(short8*)&As[ks & 7][mt * 16 + l15][quad * 8];
        #pragma unroll
        for (int nt = 0; nt < 8; ++nt)
            #pragma unroll
            for (int mt = 0; mt < 4; ++mt)
                acc[mt][nt] = __builtin_amdgcn_mfma_f32_16x16x32_bf16(af[mt], bf[cur][nt], acc[mt][nt], 0, 0, 0);
    }

    // epilogue: rs[mt][r] = sum over wave's 128 cols of tanh(q+keys)*v
    // C/D layout: col = l15, row(in 16-tile) = quad*4 + r   [m89/m91]
    float rs[4][4];
    #pragma unroll
    for (int mt = 0; mt < 4; ++mt)
        #pragma unroll
        for (int r = 0; r < 4; ++r) rs[mt][r] = 0.f;
    #pragma unroll
    for (int nt = 0; nt < 8; ++nt) {
        int g = w * 128 + nt * 16 + l15;
        float qb = q_s[g], vv = v_s[g];
        #pragma unroll
        for (int mt = 0; mt < 4; ++mt)
            #pragma unroll
            for (int r = 0; r < 4; ++r)
                rs[mt][r] += tanh_fast(qb + acc[mt][nt][r]) * vv;
    }
    #pragma unroll
    for (int m = 1; m <= 8; m <<= 1)
        #pragma unroll
        for (int mt = 0; mt < 4; ++mt)
            #pragma unroll
            for (int r = 0; r < 4; ++r)
                rs[mt][r] += __shfl_xor(rs[mt][r], m, 64);
    if (l15 == 0) {
        #pragma unroll
        for (int mt = 0; mt < 4; ++mt)
            #pragma unroll
            for (int r = 0; r < 4; ++r)
                red[w][mt * 16 + quad * 4 + r] = rs[mt][r];
    }
    __syncthreads();
    if (t < 64) {
        float sc = red[0][t] + red[1][t] + red[2][t] + red[3][t];
        scores[m0 + t] = sc;                               // linear b*2048 + s
        w_lds[t] = __expf(sc);                             // unnormalized weight, f32-safe
    }
    __syncthreads();

    // context numerator partial: thread t covers h = 2t, 2t+1.
    // Re-reads this block's own 64x512 f32 enc tile — just streamed through L2/L3,
    // so this is (mostly) not an HBM fetch. Wave reads are 512B contiguous per row.
    {
        float n0 = 0.f, n1 = 0.f;
        const float* ep = enc + m0 * 512 + t * 2;
        #pragma unroll 16
        for (int s = 0; s < 64; ++s) {
            float wv = w_lds[s];                           // LDS broadcast (same addr)
            float2 e = *(const float2*)(ep + (size_t)s * 512);
            n0 += wv * e.x; n1 += wv * e.y;
        }
        float* np = numer + b * 512 + t * 2;
        atomicAdd(np, n0);                                 // 32 tiles/batch -> light contention
        atomicAdd(np + 1, n1);
    }
}

// ---------------- kernel 4: softmax in place + finalize context ----------------
// weights = exp(sc - mx)/sum;  context = numer * exp(-mx)/sum  (same normalization,
// since numer accumulated exp(sc) unscaled).
__global__ void softmax_kernel(float* __restrict__ out, const float* __restrict__ numer) {
    int b = blockIdx.x, t = threadIdx.x, lane = t & 63, w = t >> 6;
    float* sc = out + 32768 + b * 2048;
    __shared__ float wred[4];
    float vals[8];
    float mx = -1e30f;
    #pragma unroll
    for (int i = 0; i < 8; ++i) { vals[i] = sc[t + i * 256]; mx = fmaxf(mx, vals[i]); }
    #pragma unroll
    for (int m = 32; m; m >>= 1) mx = fmaxf(mx, __shfl_xor(mx, m, 64));
    if (lane == 0) wred[w] = mx;
    __syncthreads();
    mx = fmaxf(fmaxf(wred[0], wred[1]), fmaxf(wred[2], wred[3]));
    __syncthreads();
    float s = 0.f;
    #pragma unroll
    for (int i = 0; i < 8; ++i) { vals[i] = __expf(vals[i] - mx); s += vals[i]; }
    #pragma unroll
    for (int m = 32; m; m >>= 1) s += __shfl_xor(s, m, 64);
    if (lane == 0) wred[w] = s;
    __syncthreads();
    s = wred[0] + wred[1] + wred[2] + wred[3];
    float inv = 1.0f / s;
    #pragma unroll
    for (int i = 0; i < 8; ++i) sc[t + i * 256] = vals[i] * inv;
    // finalize context: overwrite poisoned out region directly (no atomics, no pre-zero)
    float csc = __expf(-mx) * inv;
    out[b * 512 + t]       = numer[b * 512 + t] * csc;
    out[b * 512 + 256 + t] = numer[b * 512 + 256 + t] * csc;
}

extern "C" void kernel_launch(void* const* d_in, const int* in_sizes, int n_in,
                              void* d_out, int out_size, void* d_ws, size_t ws_size,
                              hipStream_t stream) {
    const float* dec = (const float*)d_in[0];
    const float* enc = (const float*)d_in[1];
    const float* wq  = (const float*)d_in[2];
    const float* wk  = (const float*)d_in[3];
    const float* v   = (const float*)d_in[4];
    float* out = (float*)d_out;

    unsigned short* wkb = (unsigned short*)d_ws;                 // 512*512*2 = 512 KiB
    float* q = (float*)((char*)d_ws + 512 * 512 * 2);            // 64*512*4  = 128 KiB
    float* numer = (float*)((char*)d_ws + 512 * 512 * 2 + 64 * 512 * 4);  // 128 KiB

    cast_wk_kernel<<<256, 256, 0, stream>>>(wk, wkb, numer);
    q_kernel<<<512, 256, 0, stream>>>(dec, wq, q);
    scores_kernel<<<2048, 256, 0, stream>>>(enc, wkb, q, v, out + 32768, numer);
    softmax_kernel<<<64, 256, 0, stream>>>(out, numer);
}

// Round 4
// 462.773 us; speedup vs baseline: 1.0959x; 1.0959x over previous
//
#include <hip/hip_runtime.h>
#include <hip/hip_bf16.h>
#include <cstdint>

// B=64, S=2048, H=512
// in: dec[64,512] f32, enc[64,2048,512] f32, Wq[512,512] f32, Wk[512,512] f32, v[512] f32
// out: context[64,512] ++ weights[64,2048]  (163840 f32)
// ws: [0,512K) Wk bf16; [512K,640K) q f32; [640K,768K) numer f32 (unnormalized context)

typedef __attribute__((ext_vector_type(8))) short short8;
typedef __attribute__((ext_vector_type(4))) float f32x4;

__device__ __forceinline__ unsigned short f2bf(float f) {
    unsigned u = __builtin_bit_cast(unsigned, f);
    u += 0x7FFFu + ((u >> 16) & 1u);       // RNE; inputs are normal floats
    return (unsigned short)(u >> 16);
}

__device__ __forceinline__ short8 cvt8(float4 a, float4 b) {
    short8 r;
    r[0] = (short)f2bf(a.x); r[1] = (short)f2bf(a.y);
    r[2] = (short)f2bf(a.z); r[3] = (short)f2bf(a.w);
    r[4] = (short)f2bf(b.x); r[5] = (short)f2bf(b.y);
    r[6] = (short)f2bf(b.z); r[7] = (short)f2bf(b.w);
    return r;
}

__device__ __forceinline__ float tanh_fast(float x) {
    // tanh(x) = 1 - 2/(exp(2x)+1); exp overflow -> inf -> rcp -> 0 -> +1 (correct limit)
    float e = __expf(2.0f * x);
    return 1.0f - 2.0f * __builtin_amdgcn_rcpf(e + 1.0f);
}

// async global->LDS, 16B per lane; dest must be wave-uniform base + lane*16
__device__ __forceinline__ void async16(const unsigned short* g, short* l) {
    __builtin_amdgcn_global_load_lds(
        (const __attribute__((address_space(1))) unsigned int*)g,
        (__attribute__((address_space(3))) unsigned int*)l, 16, 0, 0);
}

// ---------------- kernel 1: cast W_k to bf16 + zero numer accumulator ----------------
__global__ void cast_wk_kernel(const float* __restrict__ wk, unsigned short* __restrict__ wkb,
                               float* __restrict__ numer) {
    int i = (blockIdx.x * 256 + threadIdx.x) * 4;          // 256 blocks x 256 thr x 4 = 262144
    float4 f = *(const float4*)(wk + i);
    ushort4 o;
    o.x = f2bf(f.x); o.y = f2bf(f.y); o.z = f2bf(f.z); o.w = f2bf(f.w);
    *(ushort4*)(wkb + i) = o;
    if (blockIdx.x < 32) {                                 // 32*256*4 = 32768 = 64*512
        *(float4*)(numer + i) = (float4){0.f, 0.f, 0.f, 0.f};
    }
}

// ---------------- kernel 2: q = dec @ Wq^T ----------------
__global__ void q_kernel(const float* __restrict__ dec, const float* __restrict__ wq,
                         float* __restrict__ q) {
    int b  = blockIdx.x >> 3;
    int g0 = (blockIdx.x & 7) * 64;
    int t = threadIdx.x, lane = t & 63, w = t >> 6;
    __shared__ float dls[512];
    dls[t] = dec[b * 512 + t];
    dls[t + 256] = dec[b * 512 + 256 + t];
    __syncthreads();
    #pragma unroll
    for (int gi = 0; gi < 16; ++gi) {
        int g = g0 + w + gi * 4;
        float acc = 0.f;
        #pragma unroll
        for (int it = 0; it < 2; ++it) {
            int h = (it * 64 + lane) * 4;                  // wave reads 1KiB contiguous of row g
            float4 wv = *(const float4*)(wq + (size_t)g * 512 + h);
            acc += wv.x * dls[h] + wv.y * dls[h + 1] + wv.z * dls[h + 2] + wv.w * dls[h + 3];
        }
        #pragma unroll
        for (int m = 32; m; m >>= 1) acc += __shfl_xor(acc, m, 64);
        if (lane == 0) q[b * 512 + g] = acc;
    }
}

// ---------------- kernel 3: fused keys-GEMM + tanh·v row-reduce -> raw scores ----------------
// R4: M-tile 128, 512 threads (8 waves in 2Mx4N grid), 1 block/CU (LDS 92.7 KiB).
// Rationale (from R2/R3 post-mortems): the 2-phase {issue(k+1); compute(k); barrier}
// shape only works if the per-SIMD step wall exceeds loaded memory latency (~2-3K cyc).
// At 4 waves/SIMD the step wall is ~1500 cyc of issued work vs R2's ~300 -> the
// barrier's vmcnt(0) drain is covered. Also halves Wk L2 re-reads (512KB per 128 rows).
// B staged via global_load_lds (coalesced DMA, zero VGPR) exactly as R1 (proven swizzle);
// A staged to As[2] bf16 (80B pitch) via reg+cvt, issued at step top, written at step end.
__launch_bounds__(512)
__global__ void scores_kernel(const float* __restrict__ enc, const unsigned short* __restrict__ wkb,
                              const float* __restrict__ q, const float* __restrict__ v,
                              float* __restrict__ scores, float* __restrict__ numer) {
    __shared__ __align__(16) short Bs[2][512 * 32];  // 64 KiB, layout forced by global_load_lds
    __shared__ __align__(16) short As[2][128][40];   // 20 KiB, 80B pitch: 2-way banks (free)
    __shared__ float q_s[512];
    __shared__ float v_s[512];
    __shared__ float red[4][128];
    __shared__ float w_lds[128];                   // exp(sc) per tile row

    int t = threadIdx.x, lane = t & 63, w = t >> 6;      // 8 waves
    int wr = w >> 2, wc = w & 3;                         // wave grid 2 (rows) x 4 (cols)
    int quad = lane >> 4, l15 = lane & 15;
    int tile = blockIdx.x;
    int b = tile >> 4;                   // 16 tiles per batch (2048/128)
    size_t m0 = (size_t)tile * 128;

    q_s[t] = q[b * 512 + t];
    v_s[t] = v[t];

    f32x4 acc[4][8];
    #pragma unroll
    for (int i = 0; i < 4; ++i)
        #pragma unroll
        for (int j = 0; j < 8; ++j)
            acc[i][j] = (f32x4){0.f, 0.f, 0.f, 0.f};

    // A stage mapping: thread t -> row t>>2 (0..127), k-chunk t&3 (8 floats)
    int arow = t >> 2, akq = t & 3;
    const float* aptr = enc + (m0 + arow) * 512 + akq * 8;

    // B stage mapping (async): wave w stages rows {i*128 + w*16 + (lane>>2)}, i=0..3.
    // lane -> phys chunk = lane&3; logical k-chunk swizzled (same scheme as R1, proven):
    int kqs = (lane & 3) ^ ((lane >> 3) & 3);            // == (lane&3) ^ ((row&15)>>1 &3)
    const unsigned short* bgbase = wkb + (size_t)(w * 16 + (lane >> 2)) * 512 + kqs * 8;
    int blo = (w * 16 + (lane >> 2)) * 32 + (lane & 3) * 8;   // == w*512 + lane*8 shorts (linear)

    // ---- prologue: stage k-step 0 (A first, then B: cvt's A-wait leaves B in flight) ----
    {
        float4 fa0 = *(const float4*)(aptr);
        float4 fa1 = *(const float4*)(aptr + 4);
        #pragma unroll
        for (int i = 0; i < 4; ++i)
            async16(bgbase + (size_t)i * 128 * 512, &Bs[0][blo + i * 128 * 32]);
        *(short8*)&As[0][arow][akq * 8] = cvt8(fa0, fa1);
    }
    __syncthreads();                                 // Bs[0]/As[0] published

    #pragma unroll
    for (int ks = 0; ks < 16; ++ks) {
        const int cur = ks & 1, nxt = cur ^ 1;
        const int kk = ks * 32;
        // issue next step's loads FIRST: full compute phase in flight before the
        // barrier's vmcnt(0) drains them. nxt buffers were released by the barrier
        // at end of step ks-1 (all waves done reading them at ks-1).
        float4 nfa0, nfa1;
        if (ks < 15) {
            nfa0 = *(const float4*)(aptr + kk + 32);
            nfa1 = *(const float4*)(aptr + kk + 36);
            #pragma unroll
            for (int i = 0; i < 4; ++i)
                async16(bgbase + (size_t)i * 128 * 512 + kk + 32, &Bs[nxt][blo + i * 128 * 32]);
        }
        // compute current buffers
        short8 af[4];
        #pragma unroll
        for (int mt = 0; mt < 4; ++mt)
            af[mt] = *(short8*)&As[cur][wr * 64 + mt * 16 + l15][quad * 8];
        #pragma unroll
        for (int nt = 0; nt < 8; ++nt) {
            int brow = wc * 128 + nt * 16 + l15;
            short8 bf = *(short8*)&Bs[cur][brow * 32 + (quad ^ ((l15 >> 1) & 3)) * 8];
            #pragma unroll
            for (int mt = 0; mt < 4; ++mt)
                acc[mt][nt] = __builtin_amdgcn_mfma_f32_16x16x32_bf16(af[mt], bf, acc[mt][nt], 0, 0, 0);
        }
        // convert prefetched A and publish (A load had the whole MFMA phase in flight)
        if (ks < 15)
            *(short8*)&As[nxt][arow][akq * 8] = cvt8(nfa0, nfa1);
        __syncthreads();                             // drains B(ks+1) asyncs + As writes
    }

    // epilogue: rs[mt][r] = sum over wave's 128 cols of tanh(q+keys)*v
    // C/D layout: col = l15, row(in 16-tile) = quad*4 + r   [m89/m91]
    float rs[4][4];
    #pragma unroll
    for (int mt = 0; mt < 4; ++mt)
        #pragma unroll
        for (int r = 0; r < 4; ++r) rs[mt][r] = 0.f;
    #pragma unroll
    for (int nt = 0; nt < 8; ++nt) {
        int g = wc * 128 + nt * 16 + l15;
        float qb = q_s[g], vv = v_s[g];
        #pragma unroll
        for (int mt = 0; mt < 4; ++mt)
            #pragma unroll
            for (int r = 0; r < 4; ++r)
                rs[mt][r] += tanh_fast(qb + acc[mt][nt][r]) * vv;
    }
    #pragma unroll
    for (int m = 1; m <= 8; m <<= 1)
        #pragma unroll
        for (int mt = 0; mt < 4; ++mt)
            #pragma unroll
            for (int r = 0; r < 4; ++r)
                rs[mt][r] += __shfl_xor(rs[mt][r], m, 64);
    if (l15 == 0) {
        #pragma unroll
        for (int mt = 0; mt < 4; ++mt)
            #pragma unroll
            for (int r = 0; r < 4; ++r)
                red[wc][wr * 64 + mt * 16 + quad * 4 + r] = rs[mt][r];
    }
    __syncthreads();
    if (t < 128) {
        float sc = red[0][t] + red[1][t] + red[2][t] + red[3][t];
        scores[m0 + t] = sc;                               // linear b*2048 + s
        w_lds[t] = __expf(sc);                             // unnormalized weight, f32-safe
    }
    __syncthreads();

    // context numerator partial: thread t owns col h=t over the block's 128 rows.
    // Re-reads this block's own 128x512 f32 enc tile — just streamed through L2/L3.
    // Wave reads 256B contiguous per row; 4 partial sums for load ILP.
    {
        float n0 = 0.f, n1 = 0.f, n2 = 0.f, n3 = 0.f;
        const float* ep = enc + m0 * 512 + t;
        #pragma unroll 8
        for (int s = 0; s < 128; s += 4) {
            n0 += w_lds[s]     * ep[(size_t)(s)     * 512];
            n1 += w_lds[s + 1] * ep[(size_t)(s + 1) * 512];
            n2 += w_lds[s + 2] * ep[(size_t)(s + 2) * 512];
            n3 += w_lds[s + 3] * ep[(size_t)(s + 3) * 512];
        }
        atomicAdd(numer + b * 512 + t, (n0 + n1) + (n2 + n3));  // 16 partials/element
    }
}

// ---------------- kernel 4: softmax in place + finalize context ----------------
// weights = exp(sc - mx)/sum;  context = numer * exp(-mx)/sum  (same normalization,
// since numer accumulated exp(sc) unscaled).
__global__ void softmax_kernel(float* __restrict__ out, const float* __restrict__ numer) {
    int b = blockIdx.x, t = threadIdx.x, lane = t & 63, w = t >> 6;
    float* sc = out + 32768 + b * 2048;
    __shared__ float wred[4];
    float vals[8];
    float mx = -1e30f;
    #pragma unroll
    for (int i = 0; i < 8; ++i) { vals[i] = sc[t + i * 256]; mx = fmaxf(mx, vals[i]); }
    #pragma unroll
    for (int m = 32; m; m >>= 1) mx = fmaxf(mx, __shfl_xor(mx, m, 64));
    if (lane == 0) wred[w] = mx;
    __syncthreads();
    mx = fmaxf(fmaxf(wred[0], wred[1]), fmaxf(wred[2], wred[3]));
    __syncthreads();
    float s = 0.f;
    #pragma unroll
    for (int i = 0; i < 8; ++i) { vals[i] = __expf(vals[i] - mx); s += vals[i]; }
    #pragma unroll
    for (int m = 32; m; m >>= 1) s += __shfl_xor(s, m, 64);
    if (lane == 0) wred[w] = s;
    __syncthreads();
    s = wred[0] + wred[1] + wred[2] + wred[3];
    float inv = 1.0f / s;
    #pragma unroll
    for (int i = 0; i < 8; ++i) sc[t + i * 256] = vals[i] * inv;
    // finalize context: overwrite poisoned out region directly (no atomics, no pre-zero)
    float csc = __expf(-mx) * inv;
    out[b * 512 + t]       = numer[b * 512 + t] * csc;
    out[b * 512 + 256 + t] = numer[b * 512 + 256 + t] * csc;
}

extern "C" void kernel_launch(void* const* d_in, const int* in_sizes, int n_in,
                              void* d_out, int out_size, void* d_ws, size_t ws_size,
                              hipStream_t stream) {
    const float* dec = (const float*)d_in[0];
    const float* enc = (const float*)d_in[1];
    const float* wq  = (const float*)d_in[2];
    const float* wk  = (const float*)d_in[3];
    const float* v   = (const float*)d_in[4];
    float* out = (float*)d_out;

    unsigned short* wkb = (unsigned short*)d_ws;                 // 512*512*2 = 512 KiB
    float* q = (float*)((char*)d_ws + 512 * 512 * 2);            // 64*512*4  = 128 KiB
    float* numer = (float*)((char*)d_ws + 512 * 512 * 2 + 64 * 512 * 4);  // 128 KiB

    cast_wk_kernel<<<256, 256, 0, stream>>>(wk, wkb, numer);
    q_kernel<<<512, 256, 0, stream>>>(dec, wq, q);
    scores_kernel<<<1024, 512, 0, stream>>>(enc, wkb, q, v, out + 32768, numer);
    softmax_kernel<<<64, 256, 0, stream>>>(out, numer);
}